// Round 12
// baseline (1199.696 us; speedup 1.0000x reference)
//
#include <hip/hip_runtime.h>
#include <math.h>

#define SD 2048
#define BDIM 4096

typedef _Float16 f16;
using f16x8 = __attribute__((ext_vector_type(8))) f16;
using f32x4 = __attribute__((ext_vector_type(4))) float;

#define EPS_CROSS 4.8828125e-4f   // 2^-11
#define LSCALE    2048.0f         // 2^11

__device__ __forceinline__ void fsplit(float x, f16& h, f16& l) {
    h = (f16)x;
    l = (f16)((x - (float)h) * LSCALE);
}
__device__ __forceinline__ float fcomb(f16 h, f16 l) {
    return (float)h + (float)l * EPS_CROSS;
}
__device__ __forceinline__ void glds16(const void* g, void* l) {
    __builtin_amdgcn_global_load_lds(
        (const __attribute__((address_space(1))) unsigned int*)g,
        (__attribute__((address_space(3))) unsigned int*)l, 16, 0, 0);
}

struct GArgs {
    const f16 *Ah, *Al, *Bh, *Bl;
    f16 *CAh, *CAl; float sA, dA;
    f16 *C2h, *C2l; float s2, d2;
    f16 *CBh, *CBl; float sB, dB;
    float *C32; const float *bias, *gate;
};

// split-f16 MFMA GEMM, 128x128 tile, BK=32, global_load_lds staging,
// double-buffered LDS, counted-vmcnt 2-barrier schedule, conflict-free
// swizzle slot = k ^ ((row>>1)&3), T1 XCD remap.
// R12: 8 waves / 512 threads per block, wave-tile 32x64 -> 4 waves/SIMD
// (vs 2) at unchanged 2 blocks/CU; acc halves to 64 VGPR/wave.
template<int OUT>
__global__ __launch_bounds__(512, 4)
void gsplit_k(GArgs gz0, GArgs gz1)
{
    const GArgs g = blockIdx.z ? gz1 : gz0;
    __shared__ char smem[65536];   // 2 x (Ah 8K | Al 8K | Bh 8K | Bl 8K)
    const int tid  = threadIdx.x;
    const int lane = tid & 63, wid = tid >> 6;   // wid 0..7

    // T1: bijective XCD remap within z-slice (nwg is 256 or 512, %8==0)
    const int gx = gridDim.x, nwg = gx * gridDim.y;
    int id = blockIdx.x + gx * blockIdx.y;
    id = (id & 7) * (nwg >> 3) + (id >> 3);
    const int bx = id % gx, by = id / gx;
    const int row0 = by * 128, col0 = bx * 128;

    // ---- staging: 32 chunks (4 planes x 8) over 8 waves, 4 chunks/wave.
    const int lrow = lane >> 2;                          // row within 16-row chunk
    const int gsl  = (lane & 3) ^ ((lrow >> 1) & 3);     // conflict-free involution

    auto stage = [&](int buf, int k0) {
        #pragma unroll
        for (int j = 0; j < 4; ++j) {
            const int c = wid * 4 + j;                   // 0..31
            const int p = c >> 3, s = c & 7;
            const f16* pb = (p == 0) ? g.Ah : (p == 1) ? g.Al
                          : (p == 2) ? g.Bh : g.Bl;
            const int  rb = (p < 2) ? row0 : col0;
            const f16* gp = pb + (size_t)(rb + s * 16 + lrow) * SD + gsl * 8 + k0;
            glds16(gp, smem + buf * 32768 + p * 8192 + s * 1024);
        }
    };

    // ---- fragment read offsets (match the staging involution)
    const int lr = lane & 15, lg = lane >> 4;
    const int wm = wid >> 1, wn = wid & 1;   // wave grid 4(M) x 2(N), tile 32x64
    const int sxo = (lg ^ ((lr >> 1) & 3)) << 4;
    const int afo = (wm * 32 + lr) * 64 + sxo;   // + m*1024, m=0..1
    const int bfo = (wn * 64 + lr) * 64 + sxo;   // + n*1024, n=0..3

    f32x4 ch[2][4], cx[2][4];
    #pragma unroll
    for (int m = 0; m < 2; ++m)
    #pragma unroll
    for (int n = 0; n < 4; ++n) { ch[m][n] = (f32x4)0.f; cx[m][n] = (f32x4)0.f; }

    stage(0, 0);
    stage(1, 32);
    for (int kt = 0; kt < 64; ++kt) {
        const int cur = kt & 1;
        // gate: retire tile kt's 4 glds (oldest of 8); keep tile kt+1 in flight
        if (kt < 63) asm volatile("s_waitcnt vmcnt(4)" ::: "memory");
        else         asm volatile("s_waitcnt vmcnt(0)" ::: "memory");
        __builtin_amdgcn_s_barrier();

        const char* base = smem + cur * 32768;
        f16x8 ah[2], al[2], bh[4], bl[4];
        #pragma unroll
        for (int m = 0; m < 2; ++m) {
            ah[m] = *(const f16x8*)(base +     0 + afo + m*1024);
            al[m] = *(const f16x8*)(base +  8192 + afo + m*1024);
        }
        #pragma unroll
        for (int n = 0; n < 4; ++n) {
            bh[n] = *(const f16x8*)(base + 16384 + bfo + n*1024);
            bl[n] = *(const f16x8*)(base + 24576 + bfo + n*1024);
        }
        #pragma unroll
        for (int m = 0; m < 2; ++m)
        #pragma unroll
        for (int n = 0; n < 4; ++n) {
            ch[m][n] = __builtin_amdgcn_mfma_f32_16x16x32_f16(ah[m], bh[n], ch[m][n], 0, 0, 0);
            cx[m][n] = __builtin_amdgcn_mfma_f32_16x16x32_f16(ah[m], bl[n], cx[m][n], 0, 0, 0);
            cx[m][n] = __builtin_amdgcn_mfma_f32_16x16x32_f16(al[m], bh[n], cx[m][n], 0, 0, 0);
        }

        __builtin_amdgcn_s_barrier();            // all waves done reading buf cur
        if (kt + 2 < 64) stage(cur, (kt + 2) * 32);
    }

    // ---- epilogue: C/D layout col=lane&15, row=(lane>>4)*4+q (m89)
    const int erow = wm*32 + lg*4;   // + m*16 + q
    const int ecol = wn*64 + lr;     // + n*16

    if (OUT == 0) {
        f16* lds16 = (f16*)smem;     // [128][136]
        auto dumpPlane = [&](f16* dst, bool transp) {
            #pragma unroll
            for (int i = 0; i < 4; ++i) {
                int chunk = i * 512 + tid;
                int r = chunk >> 4, cs = chunk & 15;
                f16x8 v = *(const f16x8*)(lds16 + r * 136 + cs * 8);
                size_t go = transp ? ((size_t)(col0 + r) * SD + row0 + cs * 8)
                                   : ((size_t)(row0 + r) * SD + col0 + cs * 8);
                *(f16x8*)(dst + go) = v;
            }
        };
        auto writePair = [&](f16* dh, f16* dl, float s, float d, bool transp) {
            #pragma unroll
            for (int pl = 0; pl < 2; ++pl) {
                __syncthreads();
                #pragma unroll
                for (int m = 0; m < 2; ++m)
                #pragma unroll
                for (int n = 0; n < 4; ++n)
                #pragma unroll
                for (int q = 0; q < 4; ++q) {
                    int rl = erow + m*16 + q, cl = ecol + n*16;
                    float v  = ch[m][n][q] + EPS_CROSS * cx[m][n][q];
                    float vv = s * v + (((row0 + rl) == (col0 + cl)) ? d : 0.f);
                    f16 h, l; fsplit(vv, h, l);
                    int idx = transp ? (cl * 136 + rl) : (rl * 136 + cl);
                    lds16[idx] = pl ? l : h;
                }
                __syncthreads();
                dumpPlane(pl ? dl : dh, transp);
            }
        };
        if (g.CAh) writePair(g.CAh, g.CAl, g.sA, g.dA, false);
        if (g.C2h) writePair(g.C2h, g.C2l, g.s2, g.d2, false);
        if (g.CBh) writePair(g.CBh, g.CBl, g.sB, g.dB, true);
    } else {
        float* lds32 = (float*)smem;  // [128][68]
        #pragma unroll
        for (int h = 0; h < 2; ++h) {
            __syncthreads();
            if (wn == h) {
                #pragma unroll
                for (int m = 0; m < 2; ++m)
                #pragma unroll
                for (int n = 0; n < 4; ++n) {
                    int cl = ecol + n*16;
                    float b  = g.bias[col0 + cl];
                    float ga = g.gate[col0 + cl];
                    #pragma unroll
                    for (int q = 0; q < 4; ++q) {
                        int rl = erow + m*16 + q;
                        float v = ch[m][n][q] + EPS_CROSS * cx[m][n][q];
                        float t = v + b;
                        lds32[rl*68 + (cl - h*64)] = t * t * ga;
                    }
                }
            }
            __syncthreads();
            #pragma unroll
            for (int i = 0; i < 4; ++i) {
                int chunk = i * 512 + tid;
                int r = chunk >> 4, cs = chunk & 15;
                float4 v = *(const float4*)(lds32 + r*68 + cs*4);
                *(float4*)(g.C32 + (size_t)(row0 + r) * SD + col0 + h*64 + cs*4) = v;
            }
        }
    }
}

struct SArgs { const float* M; f16 *XAh, *XAl, *XBh, *XBl; };

__global__ __launch_bounds__(256)
void skew_split_k(SArgs sz0, SArgs sz1, float scale)
{
    const SArgs s = blockIdx.z ? sz1 : sz0;
    __shared__ float t1[32][33], t2[32][33];
    const int bx = blockIdx.x*32, by = blockIdx.y*32;
    const int tx = threadIdx.x, ty = threadIdx.y;
    #pragma unroll
    for (int r = 0; r < 32; r += 8) {
        t1[ty+r][tx] = s.M[(size_t)(by+ty+r)*SD + bx+tx];
        t2[ty+r][tx] = s.M[(size_t)(bx+ty+r)*SD + by+tx];
    }
    __syncthreads();
    #pragma unroll
    for (int r = 0; r < 32; r += 8) {
        float xs = (t1[ty+r][tx] - t2[tx][ty+r]) * scale;
        size_t idx = (size_t)(by+ty+r)*SD + bx+tx;
        f16 h, l;
        fsplit(xs, h, l);  s.XAh[idx] = h; s.XAl[idx] = l;
        fsplit(-xs, h, l); s.XBh[idx] = h; s.XBl[idx] = l;
    }
}

struct EArgs { const float* M; float cA; f16 *Ahp, *Alp; float cB; f16 *Bhp, *Blp; };

__global__ __launch_bounds__(256)
void eadd_k(EArgs ez0, EArgs ez1, float scale)
{
    const EArgs e = blockIdx.z ? ez1 : ez0;
    __shared__ float t1[32][33], t2[32][33];
    const int bx = blockIdx.x*32, by = blockIdx.y*32;
    const int tx = threadIdx.x, ty = threadIdx.y;
    #pragma unroll
    for (int r = 0; r < 32; r += 8) {
        t1[ty+r][tx] = e.M[(size_t)(by+ty+r)*SD + bx+tx];
        t2[ty+r][tx] = e.M[(size_t)(bx+ty+r)*SD + by+tx];
    }
    __syncthreads();
    #pragma unroll
    for (int r = 0; r < 32; r += 8) {
        float xs = (t1[ty+r][tx] - t2[tx][ty+r]) * scale;
        size_t idx = (size_t)(by+ty+r)*SD + bx+tx;
        f16 h, l;
        float va = fcomb(e.Ahp[idx], e.Alp[idx]) + e.cA * xs;
        fsplit(va, h, l); e.Ahp[idx] = h; e.Alp[idx] = l;
        if (e.Bhp) {
            float vb = fcomb(e.Bhp[idx], e.Blp[idx]) + e.cB * xs;
            fsplit(vb, h, l); e.Bhp[idx] = h; e.Blp[idx] = l;
        }
    }
}

__global__ __launch_bounds__(256)
void rownorm_k(const float* __restrict__ in, float* __restrict__ rn)
{
    const int row = blockIdx.x;
    const float4* p = (const float4*)(in + (size_t)row * SD);
    float ss = 0.f;
    for (int i = threadIdx.x; i < SD / 4; i += 256) {
        float4 v = p[i];
        ss += v.x*v.x + v.y*v.y + v.z*v.z + v.w*v.w;
    }
#pragma unroll
    for (int o = 32; o; o >>= 1) ss += __shfl_down(ss, o);
    __shared__ float part[4];
    if ((threadIdx.x & 63) == 0) part[threadIdx.x >> 6] = ss;
    __syncthreads();
    if (threadIdx.x == 0) {
        const float t = part[0] + part[1] + part[2] + part[3];
        rn[row] = 1.0f / sqrtf(fmaxf(t, 1e-12f));
    }
}

__global__ __launch_bounds__(256)
void nsplit_k(const float* __restrict__ in, const float* __restrict__ rn,
              f16* __restrict__ ph, f16* __restrict__ pl)
{
    const size_t gid  = (size_t)blockIdx.x * 256 + threadIdx.x;
    const size_t base = gid * 8;
    const float r = rn[(int)(base >> 11)];
    float4 a = *(const float4*)(in + base);
    float4 b = *(const float4*)(in + base + 4);
    float v[8] = {a.x, a.y, a.z, a.w, b.x, b.y, b.z, b.w};
    f16x8 h, l;
    #pragma unroll
    for (int j = 0; j < 8; ++j) {
        f16 hh, ll; fsplit(v[j] * r, hh, ll);
        h[j] = hh; l[j] = ll;
    }
    *(f16x8*)(ph + base) = h;
    *(f16x8*)(pl + base) = l;
}

__global__ __launch_bounds__(256)
void softmax_k(const float* __restrict__ q, float* __restrict__ pws,
               float* __restrict__ pout)
{
    __shared__ float red[4];
    const int tid = threadIdx.x;
    float m = -INFINITY;
    for (int i = tid; i < SD; i += 256) m = fmaxf(m, q[i]);
#pragma unroll
    for (int o = 32; o; o >>= 1) m = fmaxf(m, __shfl_down(m, o));
    if ((tid & 63) == 0) red[tid >> 6] = m;
    __syncthreads();
    const float gm = fmaxf(fmaxf(red[0], red[1]), fmaxf(red[2], red[3]));
    float s = 0.f;
    for (int i = tid; i < SD; i += 256) s += expf(q[i] - gm);
#pragma unroll
    for (int o = 32; o; o >>= 1) s += __shfl_down(s, o);
    __syncthreads();
    if ((tid & 63) == 0) red[tid >> 6] = s;
    __syncthreads();
    const float inv = 1.0f / (red[0] + red[1] + red[2] + red[3]);
    for (int i = tid; i < SD; i += 256) {
        const float val = expf(q[i] - gm) * inv;
        pws[i] = val;
        pout[i] = val;
    }
}

// ------------- host-side scheduling -------------
struct Pair { f16* h; f16* l; };

static GArgs mkG(Pair A, Pair B, Pair CA, float sA, float dA,
                 Pair C2, float s2, float d2, Pair CB, float sB, float dB)
{
    GArgs g{};
    g.Ah = A.h; g.Al = A.l; g.Bh = B.h; g.Bl = B.l;
    g.CAh = CA.h; g.CAl = CA.l; g.sA = sA; g.dA = dA;
    g.C2h = C2.h; g.C2l = C2.l; g.s2 = s2; g.d2 = d2;
    g.CBh = CB.h; g.CBl = CB.l; g.sB = sB; g.dB = dB;
    g.C32 = nullptr; g.bias = nullptr; g.gate = nullptr;
    return g;
}

struct ChainBuf { Pair p[4]; const float* Msrc; bool finalB; };

#define SC (1.0f / 16.0f)   // s = 4 squarings; theta ~ 12.8/16 = 0.8

// degree-6 Taylor (Paterson-Stockmeyer) + 4 squarings; result -> p[1]
static void expm_sched(hipStream_t st, int nz, const ChainBuf& c0, const ChainBuf& c1)
{
    const float k2 = 0.5f, k3 = 1.f/6.f, k4 = 1.f/24.f, k5 = 1.f/120.f, k6 = 1.f/720.f;
    const Pair NP{nullptr, nullptr};
    const dim3 tb(512);
    const dim3 gsq(SD/128, SD/128, nz);
    const dim3 gtr(SD/32, SD/32, nz), ttr(32, 8);

    auto G = [&](GArgs a, GArgs b) { gsplit_k<0><<<gsq, tb, 0, st>>>(a, b); };
    auto E = [&](EArgs a, EArgs b) { eadd_k<<<gtr, ttr, 0, st>>>(a, b, SC); };

    SArgs s0{c0.Msrc, c0.p[0].h, c0.p[0].l, c0.p[1].h, c0.p[1].l};
    SArgs s1{c1.Msrc, c1.p[0].h, c1.p[0].l, c1.p[1].h, c1.p[1].l};
    skew_split_k<<<gtr, ttr, 0, st>>>(s0, s1, SC);

    auto g1 = [&](const ChainBuf& c) {   // M0 = k6*Y + k4*I -> p2 ; Y -> p3
        return mkG(c.p[0], c.p[1], c.p[2], k6, k4, c.p[3], 1.f, 0.f, NP, 0.f, 0.f); };
    G(g1(c0), g1(c1));
    auto e1 = [&](const ChainBuf& c) {
        return EArgs{c.Msrc, k5, c.p[2].h, c.p[2].l, 0.f, nullptr, nullptr}; };
    E(e1(c0), e1(c1));
    auto g2 = [&](const ChainBuf& c) {   // M1 = M0*Y + k2*I -> p0
        return mkG(c.p[2], c.p[3], c.p[0], 1.f, k2, NP, 0.f, 0.f, NP, 0.f, 0.f); };
    G(g2(c0), g2(c1));
    auto e2 = [&](const ChainBuf& c) {
        return EArgs{c.Msrc, k3, c.p[0].h, c.p[0].l, 0.f, nullptr, nullptr}; };
    E(e2(c0), e2(c1));
    auto g3 = [&](const ChainBuf& c) {   // M2 = M1*Y + I -> p1 (A), p2 (B)
        return mkG(c.p[0], c.p[3], c.p[1], 1.f, 1.f, NP, 0.f, 0.f, c.p[2], 1.f, 1.f); };
    G(g3(c0), g3(c1));
    auto e3 = [&](const ChainBuf& c) {
        return EArgs{c.Msrc, 1.f, c.p[1].h, c.p[1].l, -1.f, c.p[2].h, c.p[2].l}; };
    E(e3(c0), e3(c1));

    auto sqF = [&](const ChainBuf& c, int ia, int ib, int oa, int ob) {
        return mkG(c.p[ia], c.p[ib], c.p[oa], 1.f, 0.f, NP, 0.f, 0.f, c.p[ob], 1.f, 0.f); };
    G(sqF(c0, 1, 2, 0, 3), sqF(c1, 1, 2, 0, 3));
    G(sqF(c0, 0, 3, 1, 2), sqF(c1, 0, 3, 1, 2));
    G(sqF(c0, 1, 2, 0, 3), sqF(c1, 1, 2, 0, 3));
    auto sqL = [&](const ChainBuf& c) {
        Pair ca = c.finalB ? NP : c.p[1];
        Pair cb = c.finalB ? c.p[1] : NP;
        return mkG(c.p[0], c.p[3], ca, 1.f, 0.f, NP, 0.f, 0.f, cb, 1.f, 0.f); };
    G(sqL(c0), sqL(c1));
}

extern "C" void kernel_launch(void* const* d_in, const int* in_sizes, int n_in,
                              void* d_out, int out_size, void* d_ws, size_t ws_size,
                              hipStream_t stream)
{
    const float* inputs = (const float*)d_in[0];
    const float* Mr     = (const float*)d_in[1];
    const float* Mi     = (const float*)d_in[2];
    const float* bias   = (const float*)d_in[3];
    const float* qg     = (const float*)d_in[4];
    float* out = (float*)d_out;

    const size_t PLANE = (size_t)SD * SD * sizeof(f16);   // 8 MB
    const size_t PAIRB = 2 * PLANE;                        // 16 MB
    char* wsb = (char*)d_ws;
    char* ob  = (char*)d_out;

    auto WP = [&](int i) { char* b = wsb + (size_t)i * PAIRB;
                           return Pair{(f16*)b, (f16*)(b + PLANE)}; };
    auto DP = [&](int i) { char* b = ob + (size_t)i * PAIRB;
                           return Pair{(f16*)b, (f16*)(b + PLANE)}; };

    const bool fused = ws_size >= 6 * PAIRB + 64 * 1024;
    const size_t smallOff = (fused ? 6 : 3) * PAIRB;
    float* rnorm = (float*)(wsb + smallOff);
    float* gatew = rnorm + 4096;
    float* gout  = out + (size_t)BDIM * SD;

    const dim3 tb256(256), tb512(512);
    const dim3 gsq1(SD/128, SD/128, 1);
    const dim3 gbt(SD/128, BDIM/128, 1);

    rownorm_k<<<BDIM, tb256, 0, stream>>>(inputs, rnorm);
    softmax_k<<<1, tb256, 0, stream>>>(qg, gatew, gout);

    Pair EA, EB, UF;
    int ninSlotA, ninSlotB;
    if (fused) {
        ChainBuf c0{{WP(0), WP(1), WP(2), WP(3)}, Mr, false};
        ChainBuf c1{{WP(4), WP(5), DP(0), DP(1)}, Mi, true};
        expm_sched(stream, 2, c0, c1);
        EA = WP(1); EB = WP(5); UF = WP(0);
        ninSlotA = 2; ninSlotB = 3;
    } else {
        ChainBuf c0{{WP(0), WP(1), DP(0), DP(1)}, Mr, false};
        expm_sched(stream, 1, c0, c0);
        ChainBuf c1{{WP(0), WP(2), DP(0), DP(1)}, Mi, true};
        expm_sched(stream, 1, c1, c1);
        EA = WP(1); EB = WP(2); UF = WP(0);
        ninSlotA = 1; ninSlotB = 2;
    }

    // U = EA * EB -> B-layout @ UF
    {
        GArgs u = mkG(EA, EB, Pair{nullptr,nullptr}, 0.f, 0.f,
                      Pair{nullptr,nullptr}, 0.f, 0.f, UF, 1.f, 0.f);
        gsplit_k<0><<<gsq1, tb512, 0, stream>>>(u, u);
    }
    // nin planes (rnorm .* inputs, hi/lo) into freed ws slots
    f16* ninh = (f16*)(wsb + (size_t)ninSlotA * PAIRB);
    f16* ninl = (f16*)(wsb + (size_t)ninSlotB * PAIRB);
    nsplit_k<<<(BDIM * SD / 8) / 256, tb256, 0, stream>>>(inputs, rnorm, ninh, ninl);
    // out = (nin @ U + bias)^2 * gate
    {
        GArgs b{};
        b.Ah = ninh; b.Al = ninl;
        b.Bh = UF.h; b.Bl = UF.l;
        b.C32 = out; b.bias = bias; b.gate = gatew;
        gsplit_k<2><<<gbt, tb512, 0, stream>>>(b, b);
    }

    (void)in_sizes; (void)n_in; (void)out_size;
}

// Round 13
// 1068.512 us; speedup vs baseline: 1.1228x; 1.1228x over previous
//
#include <hip/hip_runtime.h>
#include <math.h>

#define SD 2048
#define BDIM 4096

typedef _Float16 f16;
using f16x8 = __attribute__((ext_vector_type(8))) f16;
using f32x4 = __attribute__((ext_vector_type(4))) float;

#define EPS_CROSS 4.8828125e-4f   // 2^-11
#define LSCALE    2048.0f         // 2^11

__device__ __forceinline__ void fsplit(float x, f16& h, f16& l) {
    h = (f16)x;
    l = (f16)((x - (float)h) * LSCALE);
}
__device__ __forceinline__ void glds16(const void* g, void* l) {
    __builtin_amdgcn_global_load_lds(
        (const __attribute__((address_space(1))) unsigned int*)g,
        (__attribute__((address_space(3))) unsigned int*)l, 16, 0, 0);
}

struct GArgs {
    const f16 *Ah, *Al, *Bh, *Bl;
    f16 *CAh, *CAl; float sA, dA;
    f16 *C2h, *C2l; float s2, d2;
    f16 *CBh, *CBl; float sB, dB;
    float *C32; const float *bias, *gate;
    // R13: fused skew-correction  W += cX * X,  X = mscale*(M - M^T)
    const float *Msk; float mscale, cXA, cX2, cXB;
};

// split-f16 MFMA GEMM, 128x128 tile, BK=32, global_load_lds staging,
// double-buffered LDS, counted-vmcnt 2-barrier schedule, conflict-free
// swizzle slot = k ^ ((row>>1)&3), T1 XCD remap, 8 waves (32x64 wave-tile).
// R13: epilogue optionally adds cX * X[gr][gc] (X = mscale*(M - M^T)) to each
// output pair — replaces the separate eadd dispatches (e1/e2/e3).
// Note: for the transposed CB output, skewness gives -X[gc][gr] = +X[gr][gc],
// so cXB is passed already epilogue-signed.
template<int OUT>
__global__ __launch_bounds__(512, 4)
void gsplit_k(GArgs gz0, GArgs gz1)
{
    const GArgs g = blockIdx.z ? gz1 : gz0;
    __shared__ char smem[65536];   // 2 x (Ah 8K | Al 8K | Bh 8K | Bl 8K)
    const int tid  = threadIdx.x;
    const int lane = tid & 63, wid = tid >> 6;   // wid 0..7

    // T1: bijective XCD remap within z-slice (nwg is 256 or 512, %8==0)
    const int gx = gridDim.x, nwg = gx * gridDim.y;
    int id = blockIdx.x + gx * blockIdx.y;
    id = (id & 7) * (nwg >> 3) + (id >> 3);
    const int bx = id % gx, by = id / gx;
    const int row0 = by * 128, col0 = bx * 128;

    // ---- staging: 32 chunks (4 planes x 8) over 8 waves, 4 chunks/wave.
    const int lrow = lane >> 2;                          // row within 16-row chunk
    const int gsl  = (lane & 3) ^ ((lrow >> 1) & 3);     // conflict-free involution

    auto stage = [&](int buf, int k0) {
        #pragma unroll
        for (int j = 0; j < 4; ++j) {
            const int c = wid * 4 + j;                   // 0..31
            const int p = c >> 3, s = c & 7;
            const f16* pb = (p == 0) ? g.Ah : (p == 1) ? g.Al
                          : (p == 2) ? g.Bh : g.Bl;
            const int  rb = (p < 2) ? row0 : col0;
            const f16* gp = pb + (size_t)(rb + s * 16 + lrow) * SD + gsl * 8 + k0;
            glds16(gp, smem + buf * 32768 + p * 8192 + s * 1024);
        }
    };

    // ---- fragment read offsets (match the staging involution)
    const int lr = lane & 15, lg = lane >> 4;
    const int wm = wid >> 1, wn = wid & 1;   // wave grid 4(M) x 2(N), tile 32x64
    const int sxo = (lg ^ ((lr >> 1) & 3)) << 4;
    const int afo = (wm * 32 + lr) * 64 + sxo;   // + m*1024, m=0..1
    const int bfo = (wn * 64 + lr) * 64 + sxo;   // + n*1024, n=0..3

    f32x4 ch[2][4], cx[2][4];
    #pragma unroll
    for (int m = 0; m < 2; ++m)
    #pragma unroll
    for (int n = 0; n < 4; ++n) { ch[m][n] = (f32x4)0.f; cx[m][n] = (f32x4)0.f; }

    stage(0, 0);
    stage(1, 32);
    for (int kt = 0; kt < 64; ++kt) {
        const int cur = kt & 1;
        // gate: retire tile kt's 4 glds (oldest of 8); keep tile kt+1 in flight
        if (kt < 63) asm volatile("s_waitcnt vmcnt(4)" ::: "memory");
        else         asm volatile("s_waitcnt vmcnt(0)" ::: "memory");
        __builtin_amdgcn_s_barrier();

        const char* base = smem + cur * 32768;
        f16x8 ah[2], al[2], bh[4], bl[4];
        #pragma unroll
        for (int m = 0; m < 2; ++m) {
            ah[m] = *(const f16x8*)(base +     0 + afo + m*1024);
            al[m] = *(const f16x8*)(base +  8192 + afo + m*1024);
        }
        #pragma unroll
        for (int n = 0; n < 4; ++n) {
            bh[n] = *(const f16x8*)(base + 16384 + bfo + n*1024);
            bl[n] = *(const f16x8*)(base + 24576 + bfo + n*1024);
        }
        #pragma unroll
        for (int m = 0; m < 2; ++m)
        #pragma unroll
        for (int n = 0; n < 4; ++n) {
            ch[m][n] = __builtin_amdgcn_mfma_f32_16x16x32_f16(ah[m], bh[n], ch[m][n], 0, 0, 0);
            cx[m][n] = __builtin_amdgcn_mfma_f32_16x16x32_f16(ah[m], bl[n], cx[m][n], 0, 0, 0);
            cx[m][n] = __builtin_amdgcn_mfma_f32_16x16x32_f16(al[m], bh[n], cx[m][n], 0, 0, 0);
        }

        __builtin_amdgcn_s_barrier();            // all waves done reading buf cur
        if (kt + 2 < 64) stage(cur, (kt + 2) * 32);
    }

    // ---- epilogue: C/D layout col=lane&15, row=(lane>>4)*4+q (m89)
    const int erow = wm*32 + lg*4;   // + m*16 + q
    const int ecol = wn*64 + lr;     // + n*16

    if (OUT == 0) {
        f16* lds16 = (f16*)smem;     // [128][136]
        auto dumpPlane = [&](f16* dst, bool transp) {
            #pragma unroll
            for (int i = 0; i < 4; ++i) {
                int chunk = i * 512 + tid;
                int r = chunk >> 4, cs = chunk & 15;
                f16x8 v = *(const f16x8*)(lds16 + r * 136 + cs * 8);
                size_t go = transp ? ((size_t)(col0 + r) * SD + row0 + cs * 8)
                                   : ((size_t)(row0 + r) * SD + col0 + cs * 8);
                *(f16x8*)(dst + go) = v;
            }
        };
        auto writePair = [&](f16* dh, f16* dl, float s, float d, float cX, bool transp) {
            // R13: per-element skew correction (registers; L1-hot on reuse)
            float xsv[2][4][4];
            if (cX != 0.f) {
                #pragma unroll
                for (int m = 0; m < 2; ++m)
                #pragma unroll
                for (int n = 0; n < 4; ++n)
                #pragma unroll
                for (int q = 0; q < 4; ++q) {
                    const int gr = row0 + erow + m*16 + q;
                    const int gc = col0 + ecol + n*16;
                    xsv[m][n][q] = g.mscale *
                        (g.Msk[(size_t)gr * SD + gc] - g.Msk[(size_t)gc * SD + gr]);
                }
            }
            #pragma unroll
            for (int pl = 0; pl < 2; ++pl) {
                __syncthreads();
                #pragma unroll
                for (int m = 0; m < 2; ++m)
                #pragma unroll
                for (int n = 0; n < 4; ++n)
                #pragma unroll
                for (int q = 0; q < 4; ++q) {
                    int rl = erow + m*16 + q, cl = ecol + n*16;
                    float v  = ch[m][n][q] + EPS_CROSS * cx[m][n][q];
                    float vv = s * v + (((row0 + rl) == (col0 + cl)) ? d : 0.f);
                    if (cX != 0.f) vv += cX * xsv[m][n][q];
                    f16 h, l; fsplit(vv, h, l);
                    int idx = transp ? (cl * 136 + rl) : (rl * 136 + cl);
                    lds16[idx] = pl ? l : h;
                }
                __syncthreads();
                dumpPlane(pl ? dl : dh, transp);
            }
        };
        if (g.CAh) writePair(g.CAh, g.CAl, g.sA, g.dA, g.cXA, false);
        if (g.C2h) writePair(g.C2h, g.C2l, g.s2, g.d2, g.cX2, false);
        if (g.CBh) writePair(g.CBh, g.CBl, g.sB, g.dB, g.cXB, true);
    } else {
        float* lds32 = (float*)smem;  // [128][68]
        #pragma unroll
        for (int h = 0; h < 2; ++h) {
            __syncthreads();
            if (wn == h) {
                #pragma unroll
                for (int m = 0; m < 2; ++m)
                #pragma unroll
                for (int n = 0; n < 4; ++n) {
                    int cl = ecol + n*16;
                    float b  = g.bias[col0 + cl];
                    float ga = g.gate[col0 + cl];
                    #pragma unroll
                    for (int q = 0; q < 4; ++q) {
                        int rl = erow + m*16 + q;
                        float v = ch[m][n][q] + EPS_CROSS * cx[m][n][q];
                        float t = v + b;
                        lds32[rl*68 + (cl - h*64)] = t * t * ga;
                    }
                }
            }
            __syncthreads();
            #pragma unroll
            for (int i = 0; i < 4; ++i) {
                int chunk = i * 512 + tid;
                int r = chunk >> 4, cs = chunk & 15;
                float4 v = *(const float4*)(lds32 + r*68 + cs*4);
                *(float4*)(g.C32 + (size_t)(row0 + r) * SD + col0 + h*64 + cs*4) = v;
            }
        }
    }
}

struct SArgs { const float* M; f16 *XAh, *XAl, *XBh, *XBl; };

__global__ __launch_bounds__(256)
void skew_split_k(SArgs sz0, SArgs sz1, float scale)
{
    const SArgs s = blockIdx.z ? sz1 : sz0;
    __shared__ float t1[32][33], t2[32][33];
    const int bx = blockIdx.x*32, by = blockIdx.y*32;
    const int tx = threadIdx.x, ty = threadIdx.y;
    #pragma unroll
    for (int r = 0; r < 32; r += 8) {
        t1[ty+r][tx] = s.M[(size_t)(by+ty+r)*SD + bx+tx];
        t2[ty+r][tx] = s.M[(size_t)(bx+ty+r)*SD + by+tx];
    }
    __syncthreads();
    #pragma unroll
    for (int r = 0; r < 32; r += 8) {
        float xs = (t1[ty+r][tx] - t2[tx][ty+r]) * scale;
        size_t idx = (size_t)(by+ty+r)*SD + bx+tx;
        f16 h, l;
        fsplit(xs, h, l);  s.XAh[idx] = h; s.XAl[idx] = l;
        fsplit(-xs, h, l); s.XBh[idx] = h; s.XBl[idx] = l;
    }
}

__global__ __launch_bounds__(256)
void rownorm_k(const float* __restrict__ in, float* __restrict__ rn)
{
    const int row = blockIdx.x;
    const float4* p = (const float4*)(in + (size_t)row * SD);
    float ss = 0.f;
    for (int i = threadIdx.x; i < SD / 4; i += 256) {
        float4 v = p[i];
        ss += v.x*v.x + v.y*v.y + v.z*v.z + v.w*v.w;
    }
#pragma unroll
    for (int o = 32; o; o >>= 1) ss += __shfl_down(ss, o);
    __shared__ float part[4];
    if ((threadIdx.x & 63) == 0) part[threadIdx.x >> 6] = ss;
    __syncthreads();
    if (threadIdx.x == 0) {
        const float t = part[0] + part[1] + part[2] + part[3];
        rn[row] = 1.0f / sqrtf(fmaxf(t, 1e-12f));
    }
}

__global__ __launch_bounds__(256)
void nsplit_k(const float* __restrict__ in, const float* __restrict__ rn,
              f16* __restrict__ ph, f16* __restrict__ pl)
{
    const size_t gid  = (size_t)blockIdx.x * 256 + threadIdx.x;
    const size_t base = gid * 8;
    const float r = rn[(int)(base >> 11)];
    float4 a = *(const float4*)(in + base);
    float4 b = *(const float4*)(in + base + 4);
    float v[8] = {a.x, a.y, a.z, a.w, b.x, b.y, b.z, b.w};
    f16x8 h, l;
    #pragma unroll
    for (int j = 0; j < 8; ++j) {
        f16 hh, ll; fsplit(v[j] * r, hh, ll);
        h[j] = hh; l[j] = ll;
    }
    *(f16x8*)(ph + base) = h;
    *(f16x8*)(pl + base) = l;
}

__global__ __launch_bounds__(256)
void softmax_k(const float* __restrict__ q, float* __restrict__ pws,
               float* __restrict__ pout)
{
    __shared__ float red[4];
    const int tid = threadIdx.x;
    float m = -INFINITY;
    for (int i = tid; i < SD; i += 256) m = fmaxf(m, q[i]);
#pragma unroll
    for (int o = 32; o; o >>= 1) m = fmaxf(m, __shfl_down(m, o));
    if ((tid & 63) == 0) red[tid >> 6] = m;
    __syncthreads();
    const float gm = fmaxf(fmaxf(red[0], red[1]), fmaxf(red[2], red[3]));
    float s = 0.f;
    for (int i = tid; i < SD; i += 256) s += expf(q[i] - gm);
#pragma unroll
    for (int o = 32; o; o >>= 1) s += __shfl_down(s, o);
    __syncthreads();
    if ((tid & 63) == 0) red[tid >> 6] = s;
    __syncthreads();
    const float inv = 1.0f / (red[0] + red[1] + red[2] + red[3]);
    for (int i = tid; i < SD; i += 256) {
        const float val = expf(q[i] - gm) * inv;
        pws[i] = val;
        pout[i] = val;
    }
}

// ------------- host-side scheduling -------------
struct Pair { f16* h; f16* l; };

static GArgs mkG(Pair A, Pair B, Pair CA, float sA, float dA,
                 Pair C2, float s2, float d2, Pair CB, float sB, float dB,
                 const float* Msk = nullptr, float mscale = 0.f,
                 float cXA = 0.f, float cX2 = 0.f, float cXB = 0.f)
{
    GArgs g{};
    g.Ah = A.h; g.Al = A.l; g.Bh = B.h; g.Bl = B.l;
    g.CAh = CA.h; g.CAl = CA.l; g.sA = sA; g.dA = dA;
    g.C2h = C2.h; g.C2l = C2.l; g.s2 = s2; g.d2 = d2;
    g.CBh = CB.h; g.CBl = CB.l; g.sB = sB; g.dB = dB;
    g.C32 = nullptr; g.bias = nullptr; g.gate = nullptr;
    g.Msk = Msk; g.mscale = mscale; g.cXA = cXA; g.cX2 = cX2; g.cXB = cXB;
    return g;
}

struct ChainBuf { Pair p[4]; const float* Msrc; bool finalB; };

#define SC (1.0f / 16.0f)   // s = 4 squarings; theta ~ 12.8/16 = 0.8

// degree-6 Taylor (Paterson-Stockmeyer) + 4 squarings; result -> p[1].
// R13: the +c*X corrections (old e1/e2/e3) are fused into G1/G2/G3 epilogues.
static void expm_sched(hipStream_t st, int nz, const ChainBuf& c0, const ChainBuf& c1)
{
    const float k2 = 0.5f, k3 = 1.f/6.f, k4 = 1.f/24.f, k5 = 1.f/120.f, k6 = 1.f/720.f;
    const Pair NP{nullptr, nullptr};
    const dim3 tb(512);
    const dim3 gsq(SD/128, SD/128, nz);
    const dim3 gtr(SD/32, SD/32, nz), ttr(32, 8);

    auto G = [&](GArgs a, GArgs b) { gsplit_k<0><<<gsq, tb, 0, st>>>(a, b); };

    SArgs s0{c0.Msrc, c0.p[0].h, c0.p[0].l, c0.p[1].h, c0.p[1].l};
    SArgs s1{c1.Msrc, c1.p[0].h, c1.p[0].l, c1.p[1].h, c1.p[1].l};
    skew_split_k<<<gtr, ttr, 0, st>>>(s0, s1, SC);

    auto g1 = [&](const ChainBuf& c) {   // M0 = k6*Y + k4*I + k5*X -> p2 ; Y -> p3
        return mkG(c.p[0], c.p[1], c.p[2], k6, k4, c.p[3], 1.f, 0.f, NP, 0.f, 0.f,
                   c.Msrc, SC, k5, 0.f, 0.f); };
    G(g1(c0), g1(c1));
    auto g2 = [&](const ChainBuf& c) {   // M1 = M0*Y + k2*I + k3*X -> p0
        return mkG(c.p[2], c.p[3], c.p[0], 1.f, k2, NP, 0.f, 0.f, NP, 0.f, 0.f,
                   c.Msrc, SC, k3, 0.f, 0.f); };
    G(g2(c0), g2(c1));
    auto g3 = [&](const ChainBuf& c) {   // M2 = M1*Y + I + X -> p1 (A), p2 (B, -X -> +xs)
        return mkG(c.p[0], c.p[3], c.p[1], 1.f, 1.f, NP, 0.f, 0.f, c.p[2], 1.f, 1.f,
                   c.Msrc, SC, 1.f, 0.f, 1.f); };
    G(g3(c0), g3(c1));

    auto sqF = [&](const ChainBuf& c, int ia, int ib, int oa, int ob) {
        return mkG(c.p[ia], c.p[ib], c.p[oa], 1.f, 0.f, NP, 0.f, 0.f, c.p[ob], 1.f, 0.f); };
    G(sqF(c0, 1, 2, 0, 3), sqF(c1, 1, 2, 0, 3));
    G(sqF(c0, 0, 3, 1, 2), sqF(c1, 0, 3, 1, 2));
    G(sqF(c0, 1, 2, 0, 3), sqF(c1, 1, 2, 0, 3));
    auto sqL = [&](const ChainBuf& c) {
        Pair ca = c.finalB ? NP : c.p[1];
        Pair cb = c.finalB ? c.p[1] : NP;
        return mkG(c.p[0], c.p[3], ca, 1.f, 0.f, NP, 0.f, 0.f, cb, 1.f, 0.f); };
    G(sqL(c0), sqL(c1));
}

extern "C" void kernel_launch(void* const* d_in, const int* in_sizes, int n_in,
                              void* d_out, int out_size, void* d_ws, size_t ws_size,
                              hipStream_t stream)
{
    const float* inputs = (const float*)d_in[0];
    const float* Mr     = (const float*)d_in[1];
    const float* Mi     = (const float*)d_in[2];
    const float* bias   = (const float*)d_in[3];
    const float* qg     = (const float*)d_in[4];
    float* out = (float*)d_out;

    const size_t PLANE = (size_t)SD * SD * sizeof(f16);   // 8 MB
    const size_t PAIRB = 2 * PLANE;                        // 16 MB
    char* wsb = (char*)d_ws;
    char* ob  = (char*)d_out;

    auto WP = [&](int i) { char* b = wsb + (size_t)i * PAIRB;
                           return Pair{(f16*)b, (f16*)(b + PLANE)}; };
    auto DP = [&](int i) { char* b = ob + (size_t)i * PAIRB;
                           return Pair{(f16*)b, (f16*)(b + PLANE)}; };

    const bool fused = ws_size >= 6 * PAIRB + 64 * 1024;
    const size_t smallOff = (fused ? 6 : 3) * PAIRB;
    float* rnorm = (float*)(wsb + smallOff);
    float* gatew = rnorm + 4096;
    float* gout  = out + (size_t)BDIM * SD;

    const dim3 tb256(256), tb512(512);
    const dim3 gsq1(SD/128, SD/128, 1);
    const dim3 gbt(SD/128, BDIM/128, 1);

    rownorm_k<<<BDIM, tb256, 0, stream>>>(inputs, rnorm);
    softmax_k<<<1, tb256, 0, stream>>>(qg, gatew, gout);

    Pair EA, EB, UF;
    int ninSlotA, ninSlotB;
    if (fused) {
        ChainBuf c0{{WP(0), WP(1), WP(2), WP(3)}, Mr, false};
        ChainBuf c1{{WP(4), WP(5), DP(0), DP(1)}, Mi, true};
        expm_sched(stream, 2, c0, c1);
        EA = WP(1); EB = WP(5); UF = WP(0);
        ninSlotA = 2; ninSlotB = 3;
    } else {
        ChainBuf c0{{WP(0), WP(1), DP(0), DP(1)}, Mr, false};
        expm_sched(stream, 1, c0, c0);
        ChainBuf c1{{WP(0), WP(2), DP(0), DP(1)}, Mi, true};
        expm_sched(stream, 1, c1, c1);
        EA = WP(1); EB = WP(2); UF = WP(0);
        ninSlotA = 1; ninSlotB = 2;
    }

    // U = EA * EB -> B-layout @ UF
    {
        GArgs u = mkG(EA, EB, Pair{nullptr,nullptr}, 0.f, 0.f,
                      Pair{nullptr,nullptr}, 0.f, 0.f, UF, 1.f, 0.f);
        gsplit_k<0><<<gsq1, tb512, 0, stream>>>(u, u);
    }
    // nin planes (rnorm .* inputs, hi/lo) into freed ws slots
    f16* ninh = (f16*)(wsb + (size_t)ninSlotA * PAIRB);
    f16* ninl = (f16*)(wsb + (size_t)ninSlotB * PAIRB);
    nsplit_k<<<(BDIM * SD / 8) / 256, tb256, 0, stream>>>(inputs, rnorm, ninh, ninl);
    // out = (nin @ U + bias)^2 * gate
    {
        GArgs b{};
        b.Ah = ninh; b.Al = ninl;
        b.Bh = UF.h; b.Bl = UF.l;
        b.C32 = out; b.bias = bias; b.gate = gatew;
        gsplit_k<2><<<gbt, tb512, 0, stream>>>(b, b);
    }

    (void)in_sizes; (void)n_in; (void)out_size;
}